// Round 1
// baseline (71.852 us; speedup 1.0000x reference)
//
#include <hip/hip_runtime.h>
#include <hip/hip_bf16.h>

typedef __attribute__((ext_vector_type(8)))  short bf16x8;   // 8 bf16 = 4 VGPRs
typedef __attribute__((ext_vector_type(4)))  float f32x4;
typedef __attribute__((ext_vector_type(16))) float f32x16;

#define EMB_DIM 64
#define LDS_STRIDE 72   // 64 + 8 pad shorts -> 144 B row stride (9*16B, keeps
                        // 16B alignment); b128 reads at 32-row stride start at
                        // bank 4*m%32 -> even spread

// ---------------------------------------------------------------------------
// Kernel 1 (pre-pass): gather + Poincare-project each (b,s) row ONCE.
// Writes bf16-rounded embeddings E (n_tok x 64) and fp32 x2 per row to d_ws.
// Rounding/summation order identical to the previous in-block phase 1, so the
// identical-token cancellation -> acosh clamp behavior is preserved exactly.
// ---------------------------------------------------------------------------
__global__ __launch_bounds__(256) void project_kernel(
    const int* __restrict__ ids, const float* __restrict__ weight,
    short* __restrict__ E, float* __restrict__ x2g, int n_tok, int vocab)
{
    const int gt = blockIdx.x * 256 + threadIdx.x;
    const int r  = gt >> 1;                      // row
    const int h2 = gt & 1;                       // half-row (32 dims)
    if (r >= n_tok) return;                      // grid is exact; never taken

    int id = ids[r];
    id = min(max(id, 0), vocab - 1);

    const f32x4* W = (const f32x4*)(weight + (size_t)id * EMB_DIM + h2 * 32);
    f32x4 v[8];
    #pragma unroll
    for (int k = 0; k < 8; ++k) v[k] = W[k];     // 8 independent 16B loads

    float s = 0.f;
    #pragma unroll
    for (int k = 0; k < 8; ++k)
        s += v[k].x * v[k].x + v[k].y * v[k].y + v[k].z * v[k].z + v[k].w * v[k].w;
    s += __shfl_xor(s, 1);                       // full-row ||x||^2

    const float max_norm = 0.99999f;             // (1 - PROJ_EPS)/sqrt(C)
    float nrm = sqrtf(s);
    float mul = (nrm > max_norm) ? (max_norm / fmaxf(nrm, 1e-12f)) : 1.f;

    const float* vf = (const float*)v;
    bf16x8 hv[4];
    float s2 = 0.f;
    #pragma unroll
    for (int k = 0; k < 32; ++k) {
        __hip_bfloat16 hb = __float2bfloat16(vf[k] * mul);
        float hf = __bfloat162float(hb);
        s2 += hf * hf;
        hv[k >> 3][k & 7] = __builtin_bit_cast(short, hb);
    }
    s2 += __shfl_xor(s2, 1);                     // x2 of the rounded row

    bf16x8* dst = (bf16x8*)(E + (size_t)r * EMB_DIM + h2 * 32);
    #pragma unroll
    for (int k = 0; k < 4; ++k) dst[k] = hv[k];  // coalesced 16B stores
    if (h2 == 0) x2g[r] = s2;
}

// ---------------------------------------------------------------------------
// Kernel 2 (main): 64x64 output tile per block, 256 threads (4 waves).
// Phase 1 is now a coalesced L2-resident copy of 128 bf16 rows + x2.
// Phase 2: per wave one 32x32 tile via 4x mfma_f32_32x32x16_bf16 (K=64),
// fast-math acosh epilogue, nontemporal coalesced stores.
// ---------------------------------------------------------------------------
__global__ __launch_bounds__(256) void bias_kernel(
    const short* __restrict__ E, const float* __restrict__ x2g,
    const float* __restrict__ scale_p, float* __restrict__ out, int S)
{
    __shared__ short Es[128 * LDS_STRIDE];   // rows 0-63: i-rows, 64-127: j-rows
    __shared__ float x2s[128];

    const int b  = blockIdx.z;
    const int i0 = blockIdx.y * 64;
    const int j0 = blockIdx.x * 64;
    const int t  = threadIdx.x;

    // ---------------- Phase 1: L2-resident copy ----------------
    {
        const int r    = t >> 1;                 // 0..127: LDS row
        const int h2   = t & 1;                  // half-row (32 dims)
        const int lrow = (r < 64) ? (i0 + r) : (j0 + r - 64);
        const size_t erow = (size_t)b * S + lrow;

        const bf16x8* src = (const bf16x8*)(E + erow * EMB_DIM + h2 * 32);
        short* dst = Es + r * LDS_STRIDE + h2 * 32;     // 144B stride: 16B-aligned
        #pragma unroll
        for (int k = 0; k < 4; ++k) ((bf16x8*)dst)[k] = src[k];
        if (h2 == 0) x2s[r] = x2g[erow];
    }
    __syncthreads();

    // ---------------- Phase 2: MFMA + epilogue ----------------
    const int wid  = t >> 6;
    const int lane = t & 63;
    const int m  = lane & 31;
    const int h  = lane >> 5;                        // k-half selector
    const int ia = (wid >> 1) * 32;                  // local i-row base
    const int jb = (wid & 1) * 32;                   // local j-row base

    const short* Ear = Es + (ia + m) * LDS_STRIDE + h * 8;
    const short* Ebr = Es + (64 + jb + m) * LDS_STRIDE + h * 8;

    f32x16 acc = {};
    #pragma unroll
    for (int kb = 0; kb < 4; ++kb) {
        bf16x8 av = *(const bf16x8*)(Ear + kb * 16);
        bf16x8 bv = *(const bf16x8*)(Ebr + kb * 16);
        acc = __builtin_amdgcn_mfma_f32_32x32x16_bf16(av, bv, acc, 0, 0, 0);
    }

    const float xj    = x2s[64 + jb + m];
    const float scale = scale_p[0];
    const float omxj  = 1.f - xj;

    float* O = out + ((size_t)b * S + i0 + ia + 4 * h) * S + j0 + jb + m;

    #pragma unroll
    for (int g = 0; g < 4; ++g) {
        f32x4 xi4 = *(const f32x4*)(x2s + ia + g * 8 + 4 * h);   // broadcast read
        #pragma unroll
        for (int e = 0; e < 4; ++e) {
            float gv = acc[g * 4 + e];
            float xi = xi4[e];
            float sq  = fmaxf(xi + xj - 2.f * gv, 0.f);          // ||xi - xj||^2
            float den = (1.f - xi) * omxj;
            // u = arg - 1, clamped to fp32(1 + 1e-7) - 1 (matches ref clamp)
            float u = fmaxf(2.f * sq * __builtin_amdgcn_rcpf(den), 1.1920929e-7f);
            // acosh(1+u) = ln(1 + u + sqrt(u*(u+2))); v_log_f32 is log2
            float w = 1.f + u + __builtin_amdgcn_sqrtf(u * (u + 2.f));
            float dist = 0.69314718056f * __builtin_amdgcn_logf(w);
            __builtin_nontemporal_store(-scale * dist, &O[(size_t)(g * 8 + e) * S]);
        }
    }
}

// ---------------------------------------------------------------------------
// Fallback: previous verified single-kernel path (used iff ws too small).
// ---------------------------------------------------------------------------
__global__ __launch_bounds__(256) void fused_bias_kernel(
    const int* __restrict__ ids, const float* __restrict__ weight,
    const float* __restrict__ scale_p, float* __restrict__ out,
    int S, int vocab)
{
    __shared__ short Es[128 * LDS_STRIDE];
    __shared__ float x2s[128];

    const int b  = blockIdx.z;
    const int i0 = blockIdx.y * 64;
    const int j0 = blockIdx.x * 64;
    const int t  = threadIdx.x;

    {
        const int r  = t >> 1;
        const int h2 = t & 1;
        const int grow = (r < 64) ? (i0 + r) : (j0 + r - 64);
        int id = ids[(size_t)b * S + grow];
        id = min(max(id, 0), vocab - 1);

        const f32x4* W = (const f32x4*)(weight + (size_t)id * EMB_DIM + h2 * 32);
        f32x4 v[8];
        #pragma unroll
        for (int k = 0; k < 8; ++k) v[k] = W[k];

        float s = 0.f;
        #pragma unroll
        for (int k = 0; k < 8; ++k)
            s += v[k].x * v[k].x + v[k].y * v[k].y + v[k].z * v[k].z + v[k].w * v[k].w;
        s += __shfl_xor(s, 1);

        const float max_norm = 0.99999f;
        float nrm = sqrtf(s);
        float mul = (nrm > max_norm) ? (max_norm / fmaxf(nrm, 1e-12f)) : 1.f;

        const float* vf = (const float*)v;
        bf16x8 hv[4];
        float s2 = 0.f;
        #pragma unroll
        for (int k = 0; k < 32; ++k) {
            __hip_bfloat16 hb = __float2bfloat16(vf[k] * mul);
            float hf = __bfloat162float(hb);
            s2 += hf * hf;
            hv[k >> 3][k & 7] = __builtin_bit_cast(short, hb);
        }
        s2 += __shfl_xor(s2, 1);

        short* dst = Es + r * LDS_STRIDE + h2 * 32;
        #pragma unroll
        for (int k = 0; k < 4; ++k)
            *(bf16x8*)(dst + k * 8) = hv[k];
        if (h2 == 0) x2s[r] = s2;
    }
    __syncthreads();

    const int wid  = t >> 6;
    const int lane = t & 63;
    const int m  = lane & 31;
    const int h  = lane >> 5;
    const int ia = (wid >> 1) * 32;
    const int jb = (wid & 1) * 32;

    const short* Ear = Es + (ia + m) * LDS_STRIDE + h * 8;
    const short* Ebr = Es + (64 + jb + m) * LDS_STRIDE + h * 8;

    f32x16 acc = {};
    #pragma unroll
    for (int kb = 0; kb < 4; ++kb) {
        bf16x8 av = *(const bf16x8*)(Ear + kb * 16);
        bf16x8 bv = *(const bf16x8*)(Ebr + kb * 16);
        acc = __builtin_amdgcn_mfma_f32_32x32x16_bf16(av, bv, acc, 0, 0, 0);
    }

    const float xj    = x2s[64 + jb + m];
    const float scale = scale_p[0];
    const float omxj  = 1.f - xj;

    float* O = out + ((size_t)b * S + i0 + ia + 4 * h) * S + j0 + jb + m;

    #pragma unroll
    for (int g = 0; g < 4; ++g) {
        f32x4 xi4 = *(const f32x4*)(x2s + ia + g * 8 + 4 * h);
        #pragma unroll
        for (int e = 0; e < 4; ++e) {
            float gv = acc[g * 4 + e];
            float xi = xi4[e];
            float sq  = fmaxf(xi + xj - 2.f * gv, 0.f);
            float den = (1.f - xi) * omxj;
            float u = fmaxf(2.f * sq * __builtin_amdgcn_rcpf(den), 1.1920929e-7f);
            float w = 1.f + u + __builtin_amdgcn_sqrtf(u * (u + 2.f));
            float dist = 0.69314718056f * __builtin_amdgcn_logf(w);
            O[(size_t)(g * 8 + e) * S] = -scale * dist;
        }
    }
}

extern "C" void kernel_launch(void* const* d_in, const int* in_sizes, int n_in,
                              void* d_out, int out_size, void* d_ws, size_t ws_size,
                              hipStream_t stream) {
    const int*   ids     = (const int*)d_in[0];
    const float* weight  = (const float*)d_in[1];
    const float* scale_p = (const float*)d_in[2];
    float*       out     = (float*)d_out;

    const int n_tok = in_sizes[0];              // batch * seq = 4096
    const int vocab = in_sizes[1] / EMB_DIM;    // 30522
    const int S     = out_size / n_tok;         // 1024
    const int B     = n_tok / S;                // 4

    const size_t needE = (size_t)n_tok * EMB_DIM * sizeof(short);  // 512 KB
    const size_t needX = (size_t)n_tok * sizeof(float);            //  16 KB

    if (d_ws != nullptr && ws_size >= needE + needX) {
        short* E   = (short*)d_ws;
        float* x2g = (float*)((char*)d_ws + needE);

        dim3 g1((unsigned)((n_tok * 2 + 255) / 256));               // 32 blocks
        project_kernel<<<g1, 256, 0, stream>>>(ids, weight, E, x2g, n_tok, vocab);

        dim3 grid(S / 64, S / 64, B);                               // 1024 blocks
        bias_kernel<<<grid, 256, 0, stream>>>(E, x2g, scale_p, out, S);
    } else {
        dim3 grid(S / 64, S / 64, B);
        fused_bias_kernel<<<grid, 256, 0, stream>>>(ids, weight, scale_p, out, S, vocab);
    }
}